// Round 21
// baseline (69.566 us; speedup 1.0000x reference)
//
#include <hip/hip_runtime.h>
#include <hip/hip_fp8.h>

typedef int v8i __attribute__((ext_vector_type(8)));
typedef float f32x4 __attribute__((ext_vector_type(4)));

#define N_TOTAL 262144
#define D 128
#define K_TOTAL 1024
#define BN 128
#define NBLK (N_TOTAL / BN)  // 2048
#define TILEB 8192  // 64 centroids x 128 dims x 1 B fp8, 16x16x128-operand order
#define NT 16

// Kernel 1: codebook fp32 -> fp8 e4m3 (HW cvt_pk) in 16x16x128 B-operand
// order with q0/q1 SPLIT (r19/r20-verified): within each cgc 2048B block,
// lane l's bytes 0..15 at l*16, bytes 16..31 at 1024 + l*16 -> conflict-free
// contiguous ds_read_b128. nm2[k] = -0.5*||m||^2 exact fp32.
__global__ void prep_means(const float* __restrict__ means,
                           unsigned char* __restrict__ mbf8,
                           float* __restrict__ nm2) {
  int k = blockIdx.x, t = threadIdx.x;  // 1024 blocks x 64 threads
  int ts = k >> 6, c64 = k & 63;
  int cgc = c64 >> 4, c = c64 & 15;
  unsigned char* tb = mbf8 + ts * TILEB + cgc * 2048;
  float v0 = means[k * D + 2 * t];
  float v1 = means[k * D + 2 * t + 1];
  int d0 = 2 * t;
  int kq = d0 >> 5, rem0 = d0 & 31;
  int l = kq * 16 + c;
  int off = (rem0 < 16) ? (l * 16 + rem0) : (1024 + l * 16 + (rem0 - 16));
  int pk = __builtin_amdgcn_cvt_pk_fp8_f32(v0, v1, 0, false);
  *(unsigned short*)(tb + off) = (unsigned short)(pk & 0xFFFF);
  float s = v0 * v0 + v1 * v1;
#pragma unroll
  for (int m = 32; m; m >>= 1) s += __shfl_down(s, m, 64);
  if (t == 0) nm2[k] = -0.5f * s;
}

union BOp {
  uint4 q[2];
  v8i v;
};

// Kernel 2: 128 rows/block, **2 waves x 64 rows each** (af[4], bs[16]) —
// halves per-row LDS ingestion (the newly-identified co-dominant pipe:
// every wave reads the full 8KB B-tile; rows/wave 32->64 halves device LDS
// traffic 1.07->0.54 GB). Grid stays 2048 (8 blocks/CU available). T14
// reg-staging, split-q0/q1 conflict-free LDS, HW cvt_pk, max-identity loss.
__global__ __launch_bounds__(128) void kmeans_main(
    const float* __restrict__ X, const unsigned char* __restrict__ mbf8,
    const float* __restrict__ nm2, float* __restrict__ partials) {
  __shared__ __attribute__((aligned(16))) char Bs[2][TILEB];  // 16 KB dbuf
  __shared__ float m2s[K_TOTAL];                              // 4 KB
  __shared__ float x2s[BN];                                   // 512 B
  __shared__ float wsum[2];

  const int t = threadIdx.x;
  const int l = t & 63;
  const int w = t >> 6;   // 0..1
  const int lr = l & 15;  // row-in-group (A) / centroid col (B/C)
  const int kq = l >> 4;  // k-quarter (32-float slice of D=128)
  const int rot = blockIdx.x & 15;
  const long nbase = (long)blockIdx.x * BN;

  // ---- A fragments (HW cvt_pk) + exact fp32 ||x||^2 partials: 64 rows/wave ----
  v8i af[4];
  float psq[4];
#pragma unroll
  for (int g = 0; g < 4; ++g) {
    const float* xr = X + (nbase + w * 64 + g * 16 + lr) * D + kq * 32;
    v8i av;
    float sq = 0.f;
#pragma unroll
    for (int j = 0; j < 8; ++j) {
      float4 v = *(const float4*)(xr + j * 4);
      sq = fmaf(v.x, v.x, sq);
      sq = fmaf(v.y, v.y, sq);
      sq = fmaf(v.z, v.z, sq);
      sq = fmaf(v.w, v.w, sq);
      int lo = __builtin_amdgcn_cvt_pk_fp8_f32(v.x, v.y, 0, false);
      av[j] = __builtin_amdgcn_cvt_pk_fp8_f32(v.z, v.w, lo, true);
    }
    af[g] = av;
    psq[g] = sq;
  }
#pragma unroll
  for (int g = 0; g < 4; ++g) {
    float s2 = psq[g];
    s2 += __shfl_xor(s2, 16, 64);
    s2 += __shfl_xor(s2, 32, 64);
    if (kq == 0) x2s[w * 64 + g * 16 + lr] = s2;
  }

  // ---- stage nm2 into LDS (once; 128 threads x 2 float4) ----
#pragma unroll
  for (int j = 0; j < 2; ++j) {
    float4 v = ((const float4*)nm2)[t + 128 * j];
    *(float4*)(m2s + (t + 128 * j) * 4) = v;
  }

  float bs[16];  // running row maxes: [g*4 + reg]
#pragma unroll
  for (int e = 0; e < 16; ++e) bs[e] = -3.402823466e38f;

  // ---- prologue: stage tile `rot` (pure linear copy, 64 B/thread) ----
  {
    const char* src = (const char*)mbf8 + rot * TILEB;
#pragma unroll
    for (int j = 0; j < 4; ++j)
      *(uint4*)(Bs[0] + j * 2048 + t * 16) =
          *(const uint4*)(src + j * 2048 + t * 16);
  }
  __syncthreads();

#define COMPUTE_CGC(TID, BP, CGC)                                              \
  {                                                                            \
    float m2v_ = m2s[(TID) * 64 + (CGC) * 16 + lr];                            \
    f32x4 ci_ = {m2v_, m2v_, m2v_, m2v_};                                      \
    BOp bu_;                                                                   \
    bu_.q[0] = *(const uint4*)((BP) + (CGC) * 2048 + l * 16);                  \
    bu_.q[1] = *(const uint4*)((BP) + (CGC) * 2048 + 1024 + l * 16);           \
    _Pragma("unroll") for (int g_ = 0; g_ < 4; ++g_) {                         \
      f32x4 acc_ = __builtin_amdgcn_mfma_scale_f32_16x16x128_f8f6f4(           \
          af[g_], bu_.v, ci_, 0, 0, 0, 127, 0, 127);                           \
      _Pragma("unroll") for (int e_ = 0; e_ < 4; ++e_) {                       \
        bs[g_ * 4 + e_] = fmaxf(bs[g_ * 4 + e_], acc_[e_]);                    \
      }                                                                        \
    }                                                                          \
  }

  int cur = 0;
  for (int ks = 0; ks < NT; ++ks) {
    const int tid = (rot + ks) & 15;
    uint4 s0, s1, s2, s3;
    if (ks < NT - 1) {
      // issue next tile's global loads EARLY (latency hides under compute)
      const char* src = (const char*)mbf8 + (((rot + ks + 1) & 15) * TILEB);
      s0 = *(const uint4*)(src + 0 * 2048 + t * 16);
      s1 = *(const uint4*)(src + 1 * 2048 + t * 16);
      s2 = *(const uint4*)(src + 2 * 2048 + t * 16);
      s3 = *(const uint4*)(src + 3 * 2048 + t * 16);
    }
    const char* bp = Bs[cur];
    COMPUTE_CGC(tid, bp, 0);
    COMPUTE_CGC(tid, bp, 1);
    if (ks < NT - 1) {
      // mid-tile write: staging regs die here; Bs[cur^1] not being read
      char* dst = Bs[cur ^ 1];
      *(uint4*)(dst + 0 * 2048 + t * 16) = s0;
      *(uint4*)(dst + 1 * 2048 + t * 16) = s1;
      *(uint4*)(dst + 2 * 2048 + t * 16) = s2;
      *(uint4*)(dst + 3 * 2048 + t * 16) = s3;
    }
    COMPUTE_CGC(tid, bp, 2);
    COMPUTE_CGC(tid, bp, 3);
    __syncthreads();
    cur ^= 1;
  }
#undef COMPUTE_CGC

  // ---- per-row max across the 16 centroid-lanes, then loss contribution ----
  // slot (g, e) on lane (kq, lr) holds row g*16 + kq*4 + e (lanes lr share it)
  float lsum = 0.f;
#pragma unroll
  for (int e = 0; e < 16; ++e) {
    float m = bs[e];
#pragma unroll
    for (int s = 1; s < 16; s <<= 1) {
      float o = __shfl_xor(m, s, 64);
      m = fmaxf(m, o);
    }
    if (lr == 0) {
      int rowc = (e >> 2) * 16 + kq * 4 + (e & 3);
      lsum += x2s[w * 64 + rowc] - 2.0f * m;
    }
  }
#pragma unroll
  for (int s = 32; s; s >>= 1) lsum += __shfl_down(lsum, s, 64);
  if (l == 0) wsum[w] = lsum;
  __syncthreads();
  if (t == 0) partials[blockIdx.x] = wsum[0] + wsum[1];
}

// Kernel 3: deterministic fixed-order final reduction (double accum).
__global__ void reduce_loss(const float* __restrict__ partials,
                            float* __restrict__ out) {
  __shared__ double ws[4];
  int t = threadIdx.x;
  double s = 0.0;
  for (int i = t; i < NBLK; i += 256) s += (double)partials[i];
#pragma unroll
  for (int m = 32; m; m >>= 1) s += __shfl_down(s, m, 64);
  if ((t & 63) == 0) ws[t >> 6] = s;
  __syncthreads();
  if (t == 0) out[0] = (float)(ws[0] + ws[1] + ws[2] + ws[3]);
}

extern "C" void kernel_launch(void* const* d_in, const int* in_sizes, int n_in,
                              void* d_out, int out_size, void* d_ws,
                              size_t ws_size, hipStream_t stream) {
  const float* X = (const float*)d_in[0];
  const float* means = (const float*)d_in[1];
  float* out = (float*)d_out;
  char* ws = (char*)d_ws;
  unsigned char* mbf8 = (unsigned char*)ws;         // 131072 B
  float* nm2 = (float*)(ws + 131072);               // 4096 B
  float* partials = (float*)(ws + 131072 + 4096);   // 8192 B

  prep_means<<<K_TOTAL, 64, 0, stream>>>(means, mbf8, nm2);
  kmeans_main<<<NBLK, 128, 0, stream>>>(X, mbf8, nm2, partials);
  reduce_loss<<<1, 256, 0, stream>>>(partials, out);
}

// Round 22
// 61.641 us; speedup vs baseline: 1.1286x; 1.1286x over previous
//
#include <hip/hip_runtime.h>
#include <hip/hip_fp8.h>

typedef int v8i __attribute__((ext_vector_type(8)));
typedef float f32x4 __attribute__((ext_vector_type(4)));

#define N_TOTAL 262144
#define D 128
#define K_TOTAL 1024
#define TILEB 8192  // 64 centroids x 128 dims x 1 B fp8, 16x16x128-operand order
#define NT 16
#define NBLK 256  // 1 block per CU; 512 thr; 8 waves x 128 rows = 1024 rows/block

// Kernel 1: codebook fp32 -> fp8 e4m3 (HW cvt_pk) in 16x16x128 B-operand
// order with q0/q1 SPLIT (r19/r20-verified): within each cgc 2048B block,
// lane l's bytes 0..15 at l*16, bytes 16..31 at 1024 + l*16 -> conflict-free
// contiguous ds_read_b128. nm2[k] = -0.5*||m||^2 exact fp32.
__global__ void prep_means(const float* __restrict__ means,
                           unsigned char* __restrict__ mbf8,
                           float* __restrict__ nm2) {
  int k = blockIdx.x, t = threadIdx.x;  // 1024 blocks x 64 threads
  int ts = k >> 6, c64 = k & 63;
  int cgc = c64 >> 4, c = c64 & 15;
  unsigned char* tb = mbf8 + ts * TILEB + cgc * 2048;
  float v0 = means[k * D + 2 * t];
  float v1 = means[k * D + 2 * t + 1];
  int d0 = 2 * t;
  int kq = d0 >> 5, rem0 = d0 & 31;
  int l = kq * 16 + c;
  int off = (rem0 < 16) ? (l * 16 + rem0) : (1024 + l * 16 + (rem0 - 16));
  int pk = __builtin_amdgcn_cvt_pk_fp8_f32(v0, v1, 0, false);
  *(unsigned short*)(tb + off) = (unsigned short)(pk & 0xFFFF);
  float s = v0 * v0 + v1 * v1;
#pragma unroll
  for (int m = 32; m; m >>= 1) s += __shfl_down(s, m, 64);
  if (t == 0) nm2[k] = -0.5f * s;
}

union BOp {
  uint4 q[2];
  v8i v;
};

// Kernel 2: WHOLE 128KB codebook resident in LDS (139KB/block, 1 block/CU,
// grid=256). 512 threads = 8 waves x 128 rows (af[8]); ONE barrier, then a
// barrier-free MFMA loop where each 2KB B-read feeds 8 MFMAs (LDS traffic
// 1.07GB -> 268MB; MFMA-dominant per-cgc budget). 2 waves/SIMD overlap
// MFMA-blocking with VALU/LDS. loss = x2 - 2*max_k(x.m - 0.5||m||^2).
__global__ __launch_bounds__(512) void kmeans_main(
    const float* __restrict__ X, const unsigned char* __restrict__ mbf8,
    const float* __restrict__ nm2, float* __restrict__ partials) {
  __shared__ __attribute__((aligned(16))) char cb[NT * TILEB];  // 128 KB
  __shared__ float m2s[K_TOTAL];                                // 4 KB
  __shared__ float x2s[1024];                                   // 4 KB
  __shared__ float wsum[8];

  const int t = threadIdx.x;
  const int l = t & 63;
  const int w = t >> 6;   // 0..7
  const int lr = l & 15;  // row-in-group (A) / centroid col (B/C)
  const int kq = l >> 4;  // k-quarter (32-float slice of D=128)
  const long nbase = (long)blockIdx.x * 1024;

  // ---- codebook -> LDS (coalesced, conflict-free: 8KB contiguous per step) ----
#pragma unroll
  for (int j = 0; j < 16; ++j) {
    *(uint4*)(cb + j * 8192 + t * 16) =
        *(const uint4*)((const char*)mbf8 + j * 8192 + t * 16);
  }
  if (t < 256) {
    float4 v = ((const float4*)nm2)[t];
    *(float4*)(m2s + t * 4) = v;
  }

  // ---- A fragments: 128 rows/wave (HW cvt_pk) + exact fp32 x2 ----
  v8i af[8];
#pragma unroll
  for (int g = 0; g < 8; ++g) {
    const float* xr = X + (nbase + w * 128 + g * 16 + lr) * D + kq * 32;
    v8i av;
    float sq = 0.f;
#pragma unroll
    for (int j = 0; j < 8; ++j) {
      float4 v = *(const float4*)(xr + j * 4);
      sq = fmaf(v.x, v.x, sq);
      sq = fmaf(v.y, v.y, sq);
      sq = fmaf(v.z, v.z, sq);
      sq = fmaf(v.w, v.w, sq);
      int lo = __builtin_amdgcn_cvt_pk_fp8_f32(v.x, v.y, 0, false);
      av[j] = __builtin_amdgcn_cvt_pk_fp8_f32(v.z, v.w, lo, true);
    }
    af[g] = av;
    float s2 = sq + __shfl_xor(sq, 16, 64);
    s2 += __shfl_xor(s2, 32, 64);
    if (kq == 0) x2s[w * 128 + g * 16 + lr] = s2;
  }

  float bs[32];  // running row maxes: [g*4 + reg]
#pragma unroll
  for (int e = 0; e < 32; ++e) bs[e] = -3.402823466e38f;

  __syncthreads();  // codebook + m2s + x2s visible; loop is barrier-free

  // ---- main loop: read-only LDS codebook; 1 B-read feeds 8 MFMAs ----
  for (int ts = 0; ts < NT; ++ts) {
    const char* tp = cb + ts * TILEB;
    const float* mp = m2s + ts * 64 + lr;
#pragma unroll
    for (int cgc = 0; cgc < 4; ++cgc) {
      BOp bu;
      bu.q[0] = *(const uint4*)(tp + cgc * 2048 + l * 16);
      bu.q[1] = *(const uint4*)(tp + cgc * 2048 + 1024 + l * 16);
      float m2v = mp[cgc * 16];
      f32x4 ci = {m2v, m2v, m2v, m2v};
#pragma unroll
      for (int g = 0; g < 8; ++g) {
        f32x4 acc = __builtin_amdgcn_mfma_scale_f32_16x16x128_f8f6f4(
            af[g], bu.v, ci, 0, 0, 0, 127, 0, 127);
#pragma unroll
        for (int e = 0; e < 4; ++e)
          bs[g * 4 + e] = fmaxf(bs[g * 4 + e], acc[e]);
      }
    }
  }

  // ---- per-row max across the 16 centroid-lanes, then loss contribution ----
  // slot (g, e) on lane (kq, lr) holds row g*16 + kq*4 + e (lanes lr share it)
  float lsum = 0.f;
#pragma unroll
  for (int e = 0; e < 32; ++e) {
    float m = bs[e];
#pragma unroll
    for (int s = 1; s < 16; s <<= 1) {
      float o = __shfl_xor(m, s, 64);
      m = fmaxf(m, o);
    }
    if (lr == 0) {
      int rowc = (e >> 2) * 16 + kq * 4 + (e & 3);
      lsum += x2s[w * 128 + rowc] - 2.0f * m;
    }
  }
#pragma unroll
  for (int s = 32; s; s >>= 1) lsum += __shfl_down(lsum, s, 64);
  if (l == 0) wsum[w] = lsum;
  __syncthreads();
  if (t == 0) {
    float b = 0.f;
#pragma unroll
    for (int j = 0; j < 8; ++j) b += wsum[j];
    partials[blockIdx.x] = b;
  }
}

// Kernel 3: deterministic fixed-order final reduction (double accum).
__global__ void reduce_loss(const float* __restrict__ partials,
                            float* __restrict__ out) {
  __shared__ double ws[4];
  int t = threadIdx.x;
  double s = 0.0;
  for (int i = t; i < NBLK; i += 256) s += (double)partials[i];
#pragma unroll
  for (int m = 32; m; m >>= 1) s += __shfl_down(s, m, 64);
  if ((t & 63) == 0) ws[t >> 6] = s;
  __syncthreads();
  if (t == 0) out[0] = (float)(ws[0] + ws[1] + ws[2] + ws[3]);
}

extern "C" void kernel_launch(void* const* d_in, const int* in_sizes, int n_in,
                              void* d_out, int out_size, void* d_ws,
                              size_t ws_size, hipStream_t stream) {
  const float* X = (const float*)d_in[0];
  const float* means = (const float*)d_in[1];
  float* out = (float*)d_out;
  char* ws = (char*)d_ws;
  unsigned char* mbf8 = (unsigned char*)ws;         // 131072 B
  float* nm2 = (float*)(ws + 131072);               // 4096 B
  float* partials = (float*)(ws + 131072 + 4096);   // 1024 B

  prep_means<<<K_TOTAL, 64, 0, stream>>>(means, mbf8, nm2);
  kmeans_main<<<NBLK, 512, 0, stream>>>(X, mbf8, nm2, partials);
  reduce_loss<<<1, 256, 0, stream>>>(partials, out);
}